// Round 3
// baseline (1357.815 us; speedup 1.0000x reference)
//
#include <hip/hip_runtime.h>

#define NB    32768      // labels per batch
#define NC    1000       // classes
#define ND    1024       // feature dim
#define ND4   256        // float4 per row
#define MOM   0.9f
#define SEG   4          // segment blocks per class
#define CAP   96         // max rows per class bucket (Poisson mean 32.8; +11 sigma)

// ws layout (int words):
//   [0,    1000)   cursors (become counts after scatter)
//   [1024, 2024)   done tickets per class
//   [2048]         loss sum (float)
//   [2049]         n_present (float)
//   [2050]         cls_done counter (int)
//   [4096, 4096+NC*CAP)      sorted row indices (96000)
//   [131072, +NC*SEG*ND)     partial sums, float (16.4 MB), 16B-aligned
// zeroed region: words [0, 2051)

__global__ void scatter_k(const int* __restrict__ l, int* __restrict__ cursors,
                          int* __restrict__ sorted) {
    int i = blockIdx.x * blockDim.x + threadIdx.x;
    if (i < NB) {
        int c = l[i];
        int pos = atomicAdd(&cursors[c], 1);
        if (pos < CAP) sorted[c * CAP + pos] = i;
    }
}

__device__ __forceinline__ float block_sum(float v, float* sm, int t) {
    __syncthreads();
    #pragma unroll
    for (int o = 32; o > 0; o >>= 1) v += __shfl_down(v, o, 64);
    if ((t & 63) == 0) sm[t >> 6] = v;
    __syncthreads();
    if (t == 0) sm[0] = sm[0] + sm[1] + sm[2] + sm[3];
    __syncthreads();
    return sm[0];
}

// grid = NC*SEG. Segment block (c,s) sums rows j = s, s+SEG, ... of class c
// (both crops), writes a partial; the LAST segment block of class c reduces
// the SEG partials and runs the full epilogue; the last class writes out[0].
__global__ __launch_bounds__(256) void class_k(
        const float4* __restrict__ x4,
        const float4* __restrict__ ci4,
        const float4* __restrict__ cs4,
        const int* __restrict__ counts,
        const int* __restrict__ sorted,
        float4* __restrict__ part,
        int* __restrict__ done,
        float* __restrict__ loss_acc,
        int* __restrict__ cls_done,
        float* __restrict__ out) {
    int c = blockIdx.x >> 2;          // / SEG
    int s = blockIdx.x & (SEG - 1);
    int t = threadIdx.x;
    int cnt = min(counts[c], CAP);

    float4 acc = make_float4(0.f, 0.f, 0.f, 0.f);
    for (int j = s; j < cnt; j += SEG) {
        int i0 = sorted[c * CAP + j];
        float4 a = x4[(long)i0 * ND4 + t];
        float4 b = x4[((long)i0 + NB) * ND4 + t];
        acc.x += a.x + b.x;
        acc.y += a.y + b.y;
        acc.z += a.z + b.z;
        acc.w += a.w + b.w;
    }
    part[(long)blockIdx.x * ND4 + t] = acc;

    // release partials, take ticket
    __threadfence();
    __syncthreads();
    __shared__ int last;
    if (t == 0) {
        int old = atomicAdd(&done[c], 1);
        last = (old == SEG - 1) ? 1 : 0;
    }
    __syncthreads();
    if (!last) return;
    __threadfence();   // acquire: make other blocks' partials visible

    // reduce SEG partials (L2-fresh, 16 KB)
    float4 sum = make_float4(0.f, 0.f, 0.f, 0.f);
    #pragma unroll
    for (int q = 0; q < SEG; ++q) {
        float4 p = part[((long)c * SEG + q) * ND4 + t];
        sum.x += p.x; sum.y += p.y; sum.z += p.z; sum.w += p.w;
    }

    float inv = 1.0f / fmaxf((float)cnt, 1.0f);
    float4 ci = ci4[c * ND4 + t];
    float4 upd;
    upd.x = ci.x * MOM + (sum.x * inv) * (1.0f - MOM);
    upd.y = ci.y * MOM + (sum.y * inv) * (1.0f - MOM);
    upd.z = ci.z * MOM + (sum.z * inv) * (1.0f - MOM);
    upd.w = ci.w * MOM + (sum.w * inv) * (1.0f - MOM);

    __shared__ float sm[4];
    float n2 = block_sum(upd.x * upd.x + upd.y * upd.y + upd.z * upd.z + upd.w * upd.w,
                         sm, t);
    float rn = 1.0f / sqrtf(n2);

    float4 nw;
    if (cnt > 0) {
        nw.x = upd.x * rn; nw.y = upd.y * rn; nw.z = upd.z * rn; nw.w = upd.w * rn;
    } else {
        nw = ci;
    }

    float4 cs = cs4[c * ND4 + t];
    float dx = nw.x - cs.x, dy = nw.y - cs.y, dz = nw.z - cs.z, dw = nw.w - cs.w;
    float lp = block_sum(dx * dx + dy * dy + dz * dz + dw * dw, sm, t);

    if (t == 0) {
        if (cnt > 0) {
            atomicAdd(&loss_acc[0], lp);
            atomicAdd(&loss_acc[1], 1.0f);
        }
        __threadfence();
        int o2 = atomicAdd(cls_done, 1);
        if (o2 == NC - 1) {
            // all classes' loss contributions are in; read via atomic (L2)
            float s_tot = atomicAdd(&loss_acc[0], 0.0f);
            float n_tot = atomicAdd(&loss_acc[1], 0.0f);
            out[0] = s_tot / fmaxf(n_tot, 1.0f);
        }
    }
}

extern "C" void kernel_launch(void* const* d_in, const int* in_sizes, int n_in,
                              void* d_out, int out_size, void* d_ws, size_t ws_size,
                              hipStream_t stream) {
    const float* x  = (const float*)d_in[0];
    const float* ci = (const float*)d_in[1];
    const float* cs = (const float*)d_in[2];
    const int*   l  = (const int*)d_in[3];
    float* out = (float*)d_out;

    int* ws       = (int*)d_ws;
    int* cursors  = ws;
    int* done     = ws + 1024;
    float* loss   = (float*)(ws + 2048);
    int* cls_done = ws + 2050;
    int* sorted   = ws + 4096;
    float4* part  = (float4*)(ws + 131072);

    // zero cursors/done/loss/cls_done (words [0,2051))
    hipMemsetAsync(d_ws, 0, 2051 * sizeof(int), stream);

    scatter_k<<<NB / 256, 256, 0, stream>>>(l, cursors, sorted);
    class_k<<<NC * SEG, 256, 0, stream>>>((const float4*)x, (const float4*)ci,
                                          (const float4*)cs, cursors, sorted,
                                          part, done, loss, cls_done, out);
}

// Round 4
// 384.600 us; speedup vs baseline: 3.5305x; 3.5305x over previous
//
#include <hip/hip_runtime.h>

#define NB    32768      // labels per batch
#define NC    1000       // classes
#define ND    1024       // feature dim
#define ND4   256        // float4 per row
#define MOM   0.9f
#define CAP   96         // max rows per class bucket (Poisson mean 32.8)

// ws layout (int words):
//   [0,    1000)   cursors (become counts after scatter)
//   [1024, 1026)   loss accum (float: sum, n_present)
//   [2048, 2048+NC*CAP)  sorted row indices (96000)
// zeroed region: words [0, 1026)

__global__ void scatter_k(const int* __restrict__ l, int* __restrict__ cursors,
                          int* __restrict__ sorted) {
    int i = blockIdx.x * blockDim.x + threadIdx.x;
    if (i < NB) {
        int c = l[i];
        int pos = atomicAdd(&cursors[c], 1);
        if (pos < CAP) sorted[c * CAP + pos] = i;
    }
}

__device__ __forceinline__ float block_sum(float v, float* sm, int t) {
    __syncthreads();                       // protect sm reuse across calls
    #pragma unroll
    for (int o = 32; o > 0; o >>= 1) v += __shfl_down(v, o, 64);
    if ((t & 63) == 0) sm[t >> 6] = v;
    __syncthreads();
    if (t == 0) sm[0] = sm[0] + sm[1] + sm[2] + sm[3];
    __syncthreads();
    return sm[0];
}

// one block per class: gather rows (idx staged in LDS, rows unrolled x4 for
// 8 outstanding float4 loads/thread), mean, EMA, normalize, align loss.
__global__ __launch_bounds__(256) void class_k(
        const float4* __restrict__ x4,
        const float4* __restrict__ ci4,
        const float4* __restrict__ cs4,
        const int* __restrict__ counts,
        const int* __restrict__ sorted,
        float* __restrict__ loss_acc) {
    int c = blockIdx.x;
    int t = threadIdx.x;
    int cnt = min(counts[c], CAP);

    __shared__ int idx[CAP];
    if (t < cnt) idx[t] = sorted[c * CAP + t];
    __syncthreads();

    float4 acc = make_float4(0.f, 0.f, 0.f, 0.f);
    int j = 0;
    for (; j + 4 <= cnt; j += 4) {
        int i0 = idx[j], i1 = idx[j + 1], i2 = idx[j + 2], i3 = idx[j + 3];
        float4 a0 = x4[(long)i0 * ND4 + t];
        float4 b0 = x4[((long)i0 + NB) * ND4 + t];
        float4 a1 = x4[(long)i1 * ND4 + t];
        float4 b1 = x4[((long)i1 + NB) * ND4 + t];
        float4 a2 = x4[(long)i2 * ND4 + t];
        float4 b2 = x4[((long)i2 + NB) * ND4 + t];
        float4 a3 = x4[(long)i3 * ND4 + t];
        float4 b3 = x4[((long)i3 + NB) * ND4 + t];
        acc.x += ((a0.x + b0.x) + (a1.x + b1.x)) + ((a2.x + b2.x) + (a3.x + b3.x));
        acc.y += ((a0.y + b0.y) + (a1.y + b1.y)) + ((a2.y + b2.y) + (a3.y + b3.y));
        acc.z += ((a0.z + b0.z) + (a1.z + b1.z)) + ((a2.z + b2.z) + (a3.z + b3.z));
        acc.w += ((a0.w + b0.w) + (a1.w + b1.w)) + ((a2.w + b2.w) + (a3.w + b3.w));
    }
    for (; j < cnt; ++j) {
        int i0 = idx[j];
        float4 a = x4[(long)i0 * ND4 + t];
        float4 b = x4[((long)i0 + NB) * ND4 + t];
        acc.x += a.x + b.x;
        acc.y += a.y + b.y;
        acc.z += a.z + b.z;
        acc.w += a.w + b.w;
    }

    float inv = 1.0f / fmaxf((float)cnt, 1.0f);
    float4 ci = ci4[c * ND4 + t];
    float4 upd;
    upd.x = ci.x * MOM + (acc.x * inv) * (1.0f - MOM);
    upd.y = ci.y * MOM + (acc.y * inv) * (1.0f - MOM);
    upd.z = ci.z * MOM + (acc.z * inv) * (1.0f - MOM);
    upd.w = ci.w * MOM + (acc.w * inv) * (1.0f - MOM);

    __shared__ float sm[4];
    float n2 = block_sum(upd.x * upd.x + upd.y * upd.y + upd.z * upd.z + upd.w * upd.w,
                         sm, t);
    float rn = 1.0f / sqrtf(n2);

    float4 nw;
    if (cnt > 0) {
        nw.x = upd.x * rn; nw.y = upd.y * rn; nw.z = upd.z * rn; nw.w = upd.w * rn;
    } else {
        nw = ci;
    }

    float4 cs = cs4[c * ND4 + t];
    float dx = nw.x - cs.x, dy = nw.y - cs.y, dz = nw.z - cs.z, dw = nw.w - cs.w;
    float lp = block_sum(dx * dx + dy * dy + dz * dz + dw * dw, sm, t);

    if (t == 0 && cnt > 0) {
        atomicAdd(&loss_acc[0], lp);
        atomicAdd(&loss_acc[1], 1.0f);
    }
}

__global__ void final_k(const float* __restrict__ loss_acc, float* __restrict__ out) {
    out[0] = loss_acc[0] / fmaxf(loss_acc[1], 1.0f);
}

extern "C" void kernel_launch(void* const* d_in, const int* in_sizes, int n_in,
                              void* d_out, int out_size, void* d_ws, size_t ws_size,
                              hipStream_t stream) {
    const float* x  = (const float*)d_in[0];
    const float* ci = (const float*)d_in[1];
    const float* cs = (const float*)d_in[2];
    const int*   l  = (const int*)d_in[3];
    float* out = (float*)d_out;

    int* ws      = (int*)d_ws;
    int* cursors = ws;
    float* loss  = (float*)(ws + 1024);
    int* sorted  = ws + 2048;

    // zero cursors + loss accum (words [0,1026))
    hipMemsetAsync(d_ws, 0, 1026 * sizeof(int), stream);

    scatter_k<<<NB / 256, 256, 0, stream>>>(l, cursors, sorted);
    class_k<<<NC, 256, 0, stream>>>((const float4*)x, (const float4*)ci,
                                    (const float4*)cs, cursors, sorted, loss);
    final_k<<<1, 1, 0, stream>>>(loss, out);
}